// Round 1
// baseline (265.290 us; speedup 1.0000x reference)
//
#include <hip/hip_runtime.h>

#define HIST_BITS 12
#define NBINS (1 << HIST_BITS)        // 4096
#define KEY_SHIFT (32 - HIST_BITS)    // 20

// ws layout:
//   [0, 16384)        : unsigned hist[4096]
//   [16384, 16408)    : Ctrl
//   [16416, ...)      : uint2 candidate list (key, idx)
struct Ctrl {
    long long k;        // number of elements to zero
    long long r1;       // residual rank inside threshold bin (zero first r1)
    int b1;             // threshold bin (-1 => zero nothing)
    unsigned counter;   // candidate list append counter
};

__device__ __forceinline__ unsigned fkey(float f) {
    unsigned u = __float_as_uint(f);
    // monotonic map: total order on floats (incl. -0.0 < +0.0)
    return (u & 0x80000000u) ? ~u : (u | 0x80000000u);
}

// ---------------- K1: 4096-bin histogram of key top bits ----------------
__global__ void k_hist(const float* __restrict__ mask, long long n,
                       unsigned* __restrict__ ghist) {
    __shared__ unsigned sh[NBINS];
    for (int i = threadIdx.x; i < NBINS; i += blockDim.x) sh[i] = 0;
    __syncthreads();

    const long long n4 = n >> 2;
    const float4* m4 = (const float4*)mask;
    const long long stride = (long long)gridDim.x * blockDim.x;
    for (long long i = (long long)blockIdx.x * blockDim.x + threadIdx.x; i < n4; i += stride) {
        float4 v = m4[i];
        atomicAdd(&sh[fkey(v.x) >> KEY_SHIFT], 1u);
        atomicAdd(&sh[fkey(v.y) >> KEY_SHIFT], 1u);
        atomicAdd(&sh[fkey(v.z) >> KEY_SHIFT], 1u);
        atomicAdd(&sh[fkey(v.w) >> KEY_SHIFT], 1u);
    }
    // tail (n not multiple of 4)
    if (blockIdx.x == 0 && threadIdx.x == 0) {
        for (long long i = n4 * 4; i < n; ++i)
            atomicAdd(&ghist[fkey(mask[i]) >> KEY_SHIFT], 1u);
    }
    __syncthreads();
    for (int i = threadIdx.x; i < NBINS; i += blockDim.x) {
        unsigned c = sh[i];
        if (c) atomicAdd(&ghist[i], c);
    }
}

// ---------------- K2: scan histogram, find threshold bin ----------------
__global__ void k_scan(const unsigned* __restrict__ ghist, Ctrl* __restrict__ ctrl,
                       const float* __restrict__ p_ptr, long long n) {
    __shared__ long long part[256];
    __shared__ long long kk_sh;
    const int t = threadIdx.x;
    if (t == 0) {
        double p = (double)p_ptr[0];
        long long k = (long long)((1.0 - p) * (double)n);  // matches python int()
        if (k < 0) k = 0;
        if (k > n) k = n;
        kk_sh = k;
        ctrl->k = k;
        ctrl->b1 = -1;   // default: zero nothing
        ctrl->r1 = 0;
    }
    __syncthreads();
    const long long k = kk_sh;

    const int per = NBINS / 256;  // 16 bins per thread
    long long s = 0;
    for (int i = 0; i < per; ++i) s += (long long)ghist[t * per + i];
    part[t] = s;
    __syncthreads();
    // Hillis-Steele inclusive scan over 256 partials
    for (int off = 1; off < 256; off <<= 1) {
        long long add = (t >= off) ? part[t - off] : 0;
        __syncthreads();
        part[t] += add;
        __syncthreads();
    }
    if (k >= 1) {
        long long incl = part[t];
        long long excl = incl - s;
        if (excl < k && k <= incl) {   // k-th smallest is in my chunk
            long long cum = excl;
            for (int i = 0; i < per; ++i) {
                long long c = (long long)ghist[t * per + i];
                if (cum < k && k <= cum + c) {
                    ctrl->b1 = t * per + i;
                    ctrl->r1 = k - cum;   // zero first r1 (by (key,idx) order) in this bin
                    break;
                }
                cum += c;
            }
        }
    }
}

// ---------------- K3: apply + collect threshold-bin candidates ----------------
__device__ __forceinline__ float apply1(float m, float w, unsigned idx, int b1,
                                        Ctrl* ctrl, uint2* list, unsigned cap) {
    unsigned key = fkey(m);
    int bin = (int)(key >> KEY_SHIFT);
    if (bin < b1) return 0.0f;
    if (bin == b1) {
        unsigned pos = atomicAdd(&ctrl->counter, 1u);
        if (pos < cap) list[pos] = make_uint2(key, idx);
        // provisional keep; k_fix zeroes the selected subset
    }
    return w;
}

__global__ void k_apply(const float* __restrict__ w, const float* __restrict__ mask,
                        float* __restrict__ out, long long n,
                        Ctrl* __restrict__ ctrl, uint2* __restrict__ list, unsigned cap) {
    const int b1 = ctrl->b1;
    const long long n4 = n >> 2;
    const float4* m4 = (const float4*)mask;
    const float4* w4 = (const float4*)w;
    float4* o4 = (float4*)out;
    const long long stride = (long long)gridDim.x * blockDim.x;
    for (long long i = (long long)blockIdx.x * blockDim.x + threadIdx.x; i < n4; i += stride) {
        float4 m = m4[i];
        float4 wv = w4[i];
        float4 o;
        unsigned base = (unsigned)(i * 4);
        o.x = apply1(m.x, wv.x, base + 0, b1, ctrl, list, cap);
        o.y = apply1(m.y, wv.y, base + 1, b1, ctrl, list, cap);
        o.z = apply1(m.z, wv.z, base + 2, b1, ctrl, list, cap);
        o.w = apply1(m.w, wv.w, base + 3, b1, ctrl, list, cap);
        o4[i] = o;
    }
    if (blockIdx.x == 0 && threadIdx.x == 0) {
        for (long long i = n4 * 4; i < n; ++i)
            out[i] = apply1(mask[i], w[i], (unsigned)i, b1, ctrl, list, cap);
    }
}

// ---------------- K4: exact rank among candidates, zero first r1 ----------------
__global__ void k_fix(float* __restrict__ out, const Ctrl* __restrict__ ctrl,
                      const uint2* __restrict__ list, unsigned cap) {
    __shared__ uint2 ch[1024];
    unsigned nc = ctrl->counter;
    if (nc > cap) nc = cap;
    const long long r1 = ctrl->r1;
    if (ctrl->b1 < 0 || r1 <= 0) return;

    for (unsigned jb = 0; jb < nc; jb += blockDim.x) {
        unsigned j = jb + threadIdx.x;
        bool act = (j < nc);
        unsigned kj = 0, ij = 0;
        if (act) { uint2 e = list[j]; kj = e.x; ij = e.y; }
        long long rank = 0;
        for (unsigned cb = 0; cb < nc; cb += 1024) {
            unsigned mlen = nc - cb; if (mlen > 1024) mlen = 1024;
            for (unsigned u = threadIdx.x; u < mlen; u += blockDim.x) ch[u] = list[cb + u];
            __syncthreads();
            if (act) {
                for (unsigned u = 0; u < mlen; ++u) {
                    uint2 e = ch[u];
                    rank += (long long)((e.x < kj) || (e.x == kj && e.y < ij));
                }
            }
            __syncthreads();
        }
        if (act && rank < r1) out[ij] = 0.0f;
    }
}

extern "C" void kernel_launch(void* const* d_in, const int* in_sizes, int n_in,
                              void* d_out, int out_size, void* d_ws, size_t ws_size,
                              hipStream_t stream) {
    const float* weight = (const float*)d_in[0];
    const float* maskw  = (const float*)d_in[1];
    const float* pptr   = (const float*)d_in[2];
    float* out = (float*)d_out;
    const long long n = (long long)in_sizes[0];

    unsigned char* ws = (unsigned char*)d_ws;
    unsigned* hist = (unsigned*)ws;
    Ctrl* ctrl = (Ctrl*)(ws + 16384);
    uint2* list = (uint2*)(ws + 16416);
    size_t cap_sz = (ws_size > 16416) ? (ws_size - 16416) / sizeof(uint2) : 0;
    unsigned cap = (unsigned)(cap_sz > (size_t)(1u << 20) ? (1u << 20) : cap_sz);

    hipMemsetAsync(d_ws, 0, 16416, stream);
    k_hist<<<512, 256, 0, stream>>>(maskw, n, hist);
    k_scan<<<1, 256, 0, stream>>>(hist, ctrl, pptr, n);
    k_apply<<<2048, 256, 0, stream>>>(weight, maskw, out, n, ctrl, list, cap);
    k_fix<<<1, 256, 0, stream>>>(out, ctrl, list, cap);
}

// Round 2
// 256.613 us; speedup vs baseline: 1.0338x; 1.0338x over previous
//
#include <hip/hip_runtime.h>

#define HIST_BITS 12
#define NBINS (1 << HIST_BITS)        // 4096
#define KEY_SHIFT (32 - HIST_BITS)    // 20

// ws layout:
//   [0, 16384)        : unsigned hist[4096]
//   [16384, 16408)    : Ctrl
//   [16416, ...)      : uint2 candidate list (key, idx)
struct Ctrl {
    long long k;        // number of elements to zero
    long long r1;       // residual rank inside threshold bin (zero first r1)
    int b1;             // threshold bin (-1 => zero nothing)
    unsigned counter;   // candidate list append counter
};

__device__ __forceinline__ unsigned fkey(float f) {
    unsigned u = __float_as_uint(f);
    // monotonic map: total order on floats (incl. -0.0 < +0.0)
    return (u & 0x80000000u) ? ~u : (u | 0x80000000u);
}

// ---------------- K0: zero hist + ctrl (replaces hipMemsetAsync) ----------------
__global__ void k_zero(unsigned* __restrict__ hist, Ctrl* __restrict__ ctrl) {
    int i = blockIdx.x * blockDim.x + threadIdx.x;
    if (i < NBINS) hist[i] = 0;
    if (i == 0) {
        ctrl->k = 0;
        ctrl->r1 = 0;
        ctrl->b1 = -1;
        ctrl->counter = 0;
    }
}

// ---------------- K1: 4096-bin histogram of key top bits ----------------
__global__ void __launch_bounds__(256, 8)
k_hist(const float* __restrict__ mask, long long n, unsigned* __restrict__ ghist) {
    __shared__ unsigned sh[NBINS];
    for (int i = threadIdx.x; i < NBINS; i += blockDim.x) sh[i] = 0;
    __syncthreads();

    const long long n4 = n >> 2;
    const float4* m4 = (const float4*)mask;
    const long long stride = (long long)gridDim.x * blockDim.x;
    for (long long i = (long long)blockIdx.x * blockDim.x + threadIdx.x; i < n4; i += stride) {
        float4 v = m4[i];
        atomicAdd(&sh[fkey(v.x) >> KEY_SHIFT], 1u);
        atomicAdd(&sh[fkey(v.y) >> KEY_SHIFT], 1u);
        atomicAdd(&sh[fkey(v.z) >> KEY_SHIFT], 1u);
        atomicAdd(&sh[fkey(v.w) >> KEY_SHIFT], 1u);
    }
    // tail (n not multiple of 4)
    if (blockIdx.x == 0 && threadIdx.x == 0) {
        for (long long i = n4 * 4; i < n; ++i)
            atomicAdd(&ghist[fkey(mask[i]) >> KEY_SHIFT], 1u);
    }
    __syncthreads();
    for (int i = threadIdx.x; i < NBINS; i += blockDim.x) {
        unsigned c = sh[i];
        if (c) atomicAdd(&ghist[i], c);
    }
}

// ---------------- K2: scan histogram, find threshold bin ----------------
__global__ void k_scan(const unsigned* __restrict__ ghist, Ctrl* __restrict__ ctrl,
                       const float* __restrict__ p_ptr, long long n) {
    __shared__ long long part[256];
    __shared__ long long kk_sh;
    const int t = threadIdx.x;
    if (t == 0) {
        double p = (double)p_ptr[0];
        long long k = (long long)((1.0 - p) * (double)n);  // matches python int()
        if (k < 0) k = 0;
        if (k > n) k = n;
        kk_sh = k;
        ctrl->k = k;
        ctrl->b1 = -1;   // default: zero nothing
        ctrl->r1 = 0;
    }
    __syncthreads();
    const long long k = kk_sh;

    const int per = NBINS / 256;  // 16 bins per thread
    long long s = 0;
    for (int i = 0; i < per; ++i) s += (long long)ghist[t * per + i];
    part[t] = s;
    __syncthreads();
    // Hillis-Steele inclusive scan over 256 partials
    for (int off = 1; off < 256; off <<= 1) {
        long long add = (t >= off) ? part[t - off] : 0;
        __syncthreads();
        part[t] += add;
        __syncthreads();
    }
    if (k >= 1) {
        long long incl = part[t];
        long long excl = incl - s;
        if (excl < k && k <= incl) {   // k-th smallest is in my chunk
            long long cum = excl;
            for (int i = 0; i < per; ++i) {
                long long c = (long long)ghist[t * per + i];
                if (cum < k && k <= cum + c) {
                    ctrl->b1 = t * per + i;
                    ctrl->r1 = k - cum;   // zero first r1 (by (key,idx) order) in this bin
                    break;
                }
                cum += c;
            }
        }
    }
}

// ---------------- K3: apply + collect threshold-bin candidates ----------------
__device__ __forceinline__ float apply1(float m, float w, unsigned idx, int b1,
                                        Ctrl* ctrl, uint2* list, unsigned cap) {
    unsigned key = fkey(m);
    int bin = (int)(key >> KEY_SHIFT);
    if (bin < b1) return 0.0f;
    if (bin == b1) {
        unsigned pos = atomicAdd(&ctrl->counter, 1u);
        if (pos < cap) list[pos] = make_uint2(key, idx);
        // provisional keep; k_fix zeroes the selected subset
    }
    return w;
}

__global__ void __launch_bounds__(256, 8)
k_apply(const float* __restrict__ w, const float* __restrict__ mask,
        float* __restrict__ out, long long n,
        Ctrl* __restrict__ ctrl, uint2* __restrict__ list, unsigned cap) {
    const int b1 = ctrl->b1;
    const long long n4 = n >> 2;
    const float4* m4 = (const float4*)mask;
    const float4* w4 = (const float4*)w;
    float4* o4 = (float4*)out;
    const long long stride = (long long)gridDim.x * blockDim.x;
    for (long long i = (long long)blockIdx.x * blockDim.x + threadIdx.x; i < n4; i += stride) {
        float4 m = m4[i];
        float4 wv = w4[i];
        float4 o;
        unsigned base = (unsigned)(i * 4);
        o.x = apply1(m.x, wv.x, base + 0, b1, ctrl, list, cap);
        o.y = apply1(m.y, wv.y, base + 1, b1, ctrl, list, cap);
        o.z = apply1(m.z, wv.z, base + 2, b1, ctrl, list, cap);
        o.w = apply1(m.w, wv.w, base + 3, b1, ctrl, list, cap);
        o4[i] = o;
    }
    if (blockIdx.x == 0 && threadIdx.x == 0) {
        for (long long i = n4 * 4; i < n; ++i)
            out[i] = apply1(mask[i], w[i], (unsigned)i, b1, ctrl, list, cap);
    }
}

// ---------------- K4: exact rank among candidates, zero first r1 ----------------
__global__ void k_fix(float* __restrict__ out, const Ctrl* __restrict__ ctrl,
                      const uint2* __restrict__ list, unsigned cap) {
    __shared__ uint2 ch[1024];
    unsigned nc = ctrl->counter;
    if (nc > cap) nc = cap;
    const long long r1 = ctrl->r1;
    if (ctrl->b1 < 0 || r1 <= 0) return;

    for (unsigned jb = 0; jb < nc; jb += blockDim.x) {
        unsigned j = jb + threadIdx.x;
        bool act = (j < nc);
        unsigned kj = 0, ij = 0;
        if (act) { uint2 e = list[j]; kj = e.x; ij = e.y; }
        long long rank = 0;
        for (unsigned cb = 0; cb < nc; cb += 1024) {
            unsigned mlen = nc - cb; if (mlen > 1024) mlen = 1024;
            for (unsigned u = threadIdx.x; u < mlen; u += blockDim.x) ch[u] = list[cb + u];
            __syncthreads();
            if (act) {
                for (unsigned u = 0; u < mlen; ++u) {
                    uint2 e = ch[u];
                    rank += (long long)((e.x < kj) || (e.x == kj && e.y < ij));
                }
            }
            __syncthreads();
        }
        if (act && rank < r1) out[ij] = 0.0f;
    }
}

extern "C" void kernel_launch(void* const* d_in, const int* in_sizes, int n_in,
                              void* d_out, int out_size, void* d_ws, size_t ws_size,
                              hipStream_t stream) {
    const float* weight = (const float*)d_in[0];
    const float* maskw  = (const float*)d_in[1];
    const float* pptr   = (const float*)d_in[2];
    float* out = (float*)d_out;
    const long long n = (long long)in_sizes[0];

    unsigned char* ws = (unsigned char*)d_ws;
    unsigned* hist = (unsigned*)ws;
    Ctrl* ctrl = (Ctrl*)(ws + 16384);
    uint2* list = (uint2*)(ws + 16416);
    size_t cap_sz = (ws_size > 16416) ? (ws_size - 16416) / sizeof(uint2) : 0;
    unsigned cap = (unsigned)(cap_sz > (size_t)(1u << 20) ? (1u << 20) : cap_sz);

    k_zero<<<(NBINS + 255) / 256, 256, 0, stream>>>(hist, ctrl);
    k_hist<<<2048, 256, 0, stream>>>(maskw, n, hist);
    k_scan<<<1, 256, 0, stream>>>(hist, ctrl, pptr, n);
    k_apply<<<2048, 256, 0, stream>>>(weight, maskw, out, n, ctrl, list, cap);
    k_fix<<<1, 256, 0, stream>>>(out, ctrl, list, cap);
}

// Round 4
// 215.467 us; speedup vs baseline: 1.2312x; 1.1910x over previous
//
#include <hip/hip_runtime.h>

#define HIST_BITS 12
#define NBINS (1 << HIST_BITS)        // 4096
#define KEY_SHIFT (32 - HIST_BITS)    // 20
#define REP 4                         // LDS histogram replication factor

typedef float fx4 __attribute__((ext_vector_type(4)));  // clang-native, OK for nontemporal builtins

// ws layout:
//   [0, 16384)        : unsigned hist[4096]
//   [16384, 16408)    : Ctrl
//   [16416, ...)      : uint2 candidate list (key, idx)
struct Ctrl {
    long long k;        // number of elements to zero
    long long r1;       // residual rank inside threshold bin (zero first r1)
    int b1;             // threshold bin (-1 => zero nothing)
    unsigned counter;   // candidate list append counter
};

__device__ __forceinline__ unsigned fkey(float f) {
    unsigned u = __float_as_uint(f);
    // monotonic map: total order on floats (incl. -0.0 < +0.0)
    return (u & 0x80000000u) ? ~u : (u | 0x80000000u);
}

// ---------------- K0: zero hist + ctrl (replaces hipMemsetAsync) ----------------
__global__ void k_zero(unsigned* __restrict__ hist, Ctrl* __restrict__ ctrl) {
    int i = blockIdx.x * blockDim.x + threadIdx.x;
    if (i < NBINS) hist[i] = 0;
    if (i == 0) {
        ctrl->k = 0;
        ctrl->r1 = 0;
        ctrl->b1 = -1;
        ctrl->counter = 0;
    }
}

// ---------------- K1: 4096-bin histogram, 4-way replicated LDS ----------------
__global__ void __launch_bounds__(256)
k_hist(const float* __restrict__ mask, long long n, unsigned* __restrict__ ghist) {
    __shared__ unsigned sh[NBINS * REP];   // 64 KB: layout bin*REP + r
    for (int i = threadIdx.x; i < NBINS * REP; i += blockDim.x) sh[i] = 0;
    __syncthreads();

    const unsigned r = threadIdx.x & (REP - 1);
    const long long n4 = n >> 2;
    const fx4* m4 = (const fx4*)mask;
    const long long S = (long long)gridDim.x * blockDim.x;
    long long i = (long long)blockIdx.x * blockDim.x + threadIdx.x;

    // 4x ILP: four independent coalesced float4 loads in flight
    for (; i + 3 * S < n4; i += 4 * S) {
        fx4 a = m4[i];
        fx4 b = m4[i + S];
        fx4 c = m4[i + 2 * S];
        fx4 d = m4[i + 3 * S];
        atomicAdd(&sh[(fkey(a.x) >> KEY_SHIFT) * REP + r], 1u);
        atomicAdd(&sh[(fkey(a.y) >> KEY_SHIFT) * REP + r], 1u);
        atomicAdd(&sh[(fkey(a.z) >> KEY_SHIFT) * REP + r], 1u);
        atomicAdd(&sh[(fkey(a.w) >> KEY_SHIFT) * REP + r], 1u);
        atomicAdd(&sh[(fkey(b.x) >> KEY_SHIFT) * REP + r], 1u);
        atomicAdd(&sh[(fkey(b.y) >> KEY_SHIFT) * REP + r], 1u);
        atomicAdd(&sh[(fkey(b.z) >> KEY_SHIFT) * REP + r], 1u);
        atomicAdd(&sh[(fkey(b.w) >> KEY_SHIFT) * REP + r], 1u);
        atomicAdd(&sh[(fkey(c.x) >> KEY_SHIFT) * REP + r], 1u);
        atomicAdd(&sh[(fkey(c.y) >> KEY_SHIFT) * REP + r], 1u);
        atomicAdd(&sh[(fkey(c.z) >> KEY_SHIFT) * REP + r], 1u);
        atomicAdd(&sh[(fkey(c.w) >> KEY_SHIFT) * REP + r], 1u);
        atomicAdd(&sh[(fkey(d.x) >> KEY_SHIFT) * REP + r], 1u);
        atomicAdd(&sh[(fkey(d.y) >> KEY_SHIFT) * REP + r], 1u);
        atomicAdd(&sh[(fkey(d.z) >> KEY_SHIFT) * REP + r], 1u);
        atomicAdd(&sh[(fkey(d.w) >> KEY_SHIFT) * REP + r], 1u);
    }
    for (; i < n4; i += S) {
        fx4 a = m4[i];
        atomicAdd(&sh[(fkey(a.x) >> KEY_SHIFT) * REP + r], 1u);
        atomicAdd(&sh[(fkey(a.y) >> KEY_SHIFT) * REP + r], 1u);
        atomicAdd(&sh[(fkey(a.z) >> KEY_SHIFT) * REP + r], 1u);
        atomicAdd(&sh[(fkey(a.w) >> KEY_SHIFT) * REP + r], 1u);
    }
    // tail (n not multiple of 4)
    if (blockIdx.x == 0 && threadIdx.x == 0) {
        for (long long t = n4 * 4; t < n; ++t)
            atomicAdd(&ghist[fkey(mask[t]) >> KEY_SHIFT], 1u);
    }
    __syncthreads();
    for (int b = threadIdx.x; b < NBINS; b += blockDim.x) {
        unsigned s = sh[b * REP] + sh[b * REP + 1] + sh[b * REP + 2] + sh[b * REP + 3];
        if (s) atomicAdd(&ghist[b], s);
    }
}

// ---------------- K2: scan histogram, find threshold bin ----------------
__global__ void k_scan(const unsigned* __restrict__ ghist, Ctrl* __restrict__ ctrl,
                       const float* __restrict__ p_ptr, long long n) {
    __shared__ long long part[256];
    __shared__ long long kk_sh;
    const int t = threadIdx.x;
    if (t == 0) {
        double p = (double)p_ptr[0];
        long long k = (long long)((1.0 - p) * (double)n);  // matches python int()
        if (k < 0) k = 0;
        if (k > n) k = n;
        kk_sh = k;
        ctrl->k = k;
        ctrl->b1 = -1;   // default: zero nothing
        ctrl->r1 = 0;
    }
    __syncthreads();
    const long long k = kk_sh;

    const int per = NBINS / 256;  // 16 bins per thread
    long long s = 0;
    for (int i = 0; i < per; ++i) s += (long long)ghist[t * per + i];
    part[t] = s;
    __syncthreads();
    // Hillis-Steele inclusive scan over 256 partials
    for (int off = 1; off < 256; off <<= 1) {
        long long add = (t >= off) ? part[t - off] : 0;
        __syncthreads();
        part[t] += add;
        __syncthreads();
    }
    if (k >= 1) {
        long long incl = part[t];
        long long excl = incl - s;
        if (excl < k && k <= incl) {   // k-th smallest is in my chunk
            long long cum = excl;
            for (int i = 0; i < per; ++i) {
                long long c = (long long)ghist[t * per + i];
                if (cum < k && k <= cum + c) {
                    ctrl->b1 = t * per + i;
                    ctrl->r1 = k - cum;   // zero first r1 (by (key,idx) order) in this bin
                    break;
                }
                cum += c;
            }
        }
    }
}

// ---------------- K3: apply + collect threshold-bin candidates ----------------
__device__ __forceinline__ float apply1(float m, float w, unsigned idx, int b1,
                                        Ctrl* ctrl, uint2* list, unsigned cap) {
    unsigned key = fkey(m);
    int bin = (int)(key >> KEY_SHIFT);
    if (bin < b1) return 0.0f;
    if (bin == b1) {
        unsigned pos = atomicAdd(&ctrl->counter, 1u);
        if (pos < cap) list[pos] = make_uint2(key, idx);
        // provisional keep; k_fix zeroes the selected subset
    }
    return w;
}

__global__ void __launch_bounds__(256)
k_apply(const float* __restrict__ w, const float* __restrict__ mask,
        float* __restrict__ out, long long n,
        Ctrl* __restrict__ ctrl, uint2* __restrict__ list, unsigned cap) {
    const int b1 = ctrl->b1;
    const long long n4 = n >> 2;
    const fx4* m4 = (const fx4*)mask;
    const fx4* w4 = (const fx4*)w;
    fx4* o4 = (fx4*)out;
    const long long S = (long long)gridDim.x * blockDim.x;
    long long i = (long long)blockIdx.x * blockDim.x + threadIdx.x;

    // 2x ILP: mask loads cached (L3-resident), weight/out nontemporal
    for (; i + S < n4; i += 2 * S) {
        fx4 m0 = m4[i];
        fx4 m1 = m4[i + S];
        fx4 w0 = __builtin_nontemporal_load(&w4[i]);
        fx4 w1 = __builtin_nontemporal_load(&w4[i + S]);
        fx4 o0, o1;
        unsigned base0 = (unsigned)(i * 4);
        unsigned base1 = (unsigned)((i + S) * 4);
        o0.x = apply1(m0.x, w0.x, base0 + 0, b1, ctrl, list, cap);
        o0.y = apply1(m0.y, w0.y, base0 + 1, b1, ctrl, list, cap);
        o0.z = apply1(m0.z, w0.z, base0 + 2, b1, ctrl, list, cap);
        o0.w = apply1(m0.w, w0.w, base0 + 3, b1, ctrl, list, cap);
        o1.x = apply1(m1.x, w1.x, base1 + 0, b1, ctrl, list, cap);
        o1.y = apply1(m1.y, w1.y, base1 + 1, b1, ctrl, list, cap);
        o1.z = apply1(m1.z, w1.z, base1 + 2, b1, ctrl, list, cap);
        o1.w = apply1(m1.w, w1.w, base1 + 3, b1, ctrl, list, cap);
        __builtin_nontemporal_store(o0, &o4[i]);
        __builtin_nontemporal_store(o1, &o4[i + S]);
    }
    for (; i < n4; i += S) {
        fx4 m0 = m4[i];
        fx4 w0 = __builtin_nontemporal_load(&w4[i]);
        fx4 o0;
        unsigned base0 = (unsigned)(i * 4);
        o0.x = apply1(m0.x, w0.x, base0 + 0, b1, ctrl, list, cap);
        o0.y = apply1(m0.y, w0.y, base0 + 1, b1, ctrl, list, cap);
        o0.z = apply1(m0.z, w0.z, base0 + 2, b1, ctrl, list, cap);
        o0.w = apply1(m0.w, w0.w, base0 + 3, b1, ctrl, list, cap);
        __builtin_nontemporal_store(o0, &o4[i]);
    }
    if (blockIdx.x == 0 && threadIdx.x == 0) {
        for (long long t = n4 * 4; t < n; ++t)
            out[t] = apply1(mask[t], w[t], (unsigned)t, b1, ctrl, list, cap);
    }
}

// ---------------- K4: exact rank among candidates, zero first r1 ----------------
__global__ void k_fix(float* __restrict__ out, const Ctrl* __restrict__ ctrl,
                      const uint2* __restrict__ list, unsigned cap) {
    __shared__ uint2 ch[1024];
    unsigned nc = ctrl->counter;
    if (nc > cap) nc = cap;
    const long long r1 = ctrl->r1;
    if (ctrl->b1 < 0 || r1 <= 0) return;

    for (unsigned jb = 0; jb < nc; jb += blockDim.x) {
        unsigned j = jb + threadIdx.x;
        bool act = (j < nc);
        unsigned kj = 0, ij = 0;
        if (act) { uint2 e = list[j]; kj = e.x; ij = e.y; }
        long long rank = 0;
        for (unsigned cb = 0; cb < nc; cb += 1024) {
            unsigned mlen = nc - cb; if (mlen > 1024) mlen = 1024;
            for (unsigned u = threadIdx.x; u < mlen; u += blockDim.x) ch[u] = list[cb + u];
            __syncthreads();
            if (act) {
                for (unsigned u = 0; u < mlen; ++u) {
                    uint2 e = ch[u];
                    rank += (long long)((e.x < kj) || (e.x == kj && e.y < ij));
                }
            }
            __syncthreads();
        }
        if (act && rank < r1) out[ij] = 0.0f;
    }
}

extern "C" void kernel_launch(void* const* d_in, const int* in_sizes, int n_in,
                              void* d_out, int out_size, void* d_ws, size_t ws_size,
                              hipStream_t stream) {
    const float* weight = (const float*)d_in[0];
    const float* maskw  = (const float*)d_in[1];
    const float* pptr   = (const float*)d_in[2];
    float* out = (float*)d_out;
    const long long n = (long long)in_sizes[0];

    unsigned char* ws = (unsigned char*)d_ws;
    unsigned* hist = (unsigned*)ws;
    Ctrl* ctrl = (Ctrl*)(ws + 16384);
    uint2* list = (uint2*)(ws + 16416);
    size_t cap_sz = (ws_size > 16416) ? (ws_size - 16416) / sizeof(uint2) : 0;
    unsigned cap = (unsigned)(cap_sz > (size_t)(1u << 20) ? (1u << 20) : cap_sz);

    k_zero<<<(NBINS + 255) / 256, 256, 0, stream>>>(hist, ctrl);
    k_hist<<<2048, 256, 0, stream>>>(maskw, n, hist);
    k_scan<<<1, 256, 0, stream>>>(hist, ctrl, pptr, n);
    k_apply<<<2048, 256, 0, stream>>>(weight, maskw, out, n, ctrl, list, cap);
    k_fix<<<1, 256, 0, stream>>>(out, ctrl, list, cap);
}